// Round 8
// baseline (163.255 us; speedup 1.0000x reference)
//
#include <hip/hip_runtime.h>
#include <hip/hip_cooperative_groups.h>
#include <math.h>

namespace cg = cooperative_groups;

static constexpr int   B    = 256;   // batch
static constexpr int   D    = 256;   // feature dim
static constexpr int   NSV  = 512;   // P == Q
static constexpr int   RG   = 16;    // SV row-group slices
static constexpr int   RPS  = NSV / RG;   // 32 rows per set per block
static constexpr int   RPB  = 2 * RPS;    // 64 tile rows (set1 then set0)
static constexpr int   NB   = 4;          // batches per block
static constexpr int   NT   = 64;         // ONE wave per block -> no block barriers
static constexpr int   KC   = 64;         // chunk floats per row
static constexpr int   SPR  = KC / 4;     // 16 f4 slots per row
static constexpr float G    = 0.1f;
static constexpr float CSH  = 26.0f;      // fixed LSE shift; cancels in LSE0-LSE1

typedef float f32x2 __attribute__((ext_vector_type(2)));

__device__ __forceinline__ void gld16(const void* g, void* l) {
    __builtin_amdgcn_global_load_lds((__attribute__((address_space(1))) void*)g,
                                     (__attribute__((address_space(3))) void*)l,
                                     16, 0, 0);
}

__global__ __launch_bounds__(NT)
void k_coop(const float* __restrict__ x,
            const float* __restrict__ sv1,
            const float* __restrict__ sv0,
            const float* __restrict__ a1,
            const float* __restrict__ a0,
            float* __restrict__ ws,
            float* __restrict__ out)
{
    __shared__ float tile[2][RPB * KC];   // 2 x 16 KiB SV chunk buffers
    __shared__ float xls[NB * D];         // 4 KiB x rows (read as broadcasts)

    const int t     = threadIdx.x;        // == lane; == tile row
    const int rg    = blockIdx.x;
    const int bbase = blockIdx.y * NB;

    // ---- stage x rows once (linear, vmcnt slots 0..3) ----
    {
        const float* xsrc = x + (size_t)bbase * D;
        #pragma unroll
        for (int i = 0; i < (NB * D / 4) / NT; ++i) {   // 4 slots/lane
            const int f = i * NT + t;
            gld16(xsrc + f * 4, &xls[f * 4]);
        }
    }

    // SV chunk staging: linear LDS dest, XOR-swizzled global source (involution)
    auto stage = [&](int c, int buf) {
        #pragma unroll
        for (int i = 0; i < (RPB * SPR) / NT; ++i) {   // 16 slots/lane
            const int f  = i * NT + t;
            const int rr = f >> 4;          // tile row 0..63
            const int p  = f & 15;          // physical f4 slot
            const int q  = p ^ (rr & 7);    // logical slot
            const float* src = (rr < RPS)
                ? (sv1 + (size_t)(rg * RPS + rr) * D)
                : (sv0 + (size_t)(rg * RPS + (rr - RPS)) * D);
            gld16(src + c * KC + q * 4, &tile[buf][f * 4]);
        }
    };

    f32x2 ssq = {0.f, 0.f};
    f32x2 d0 = {0.f, 0.f}, d1 = {0.f, 0.f}, d2 = {0.f, 0.f}, d3 = {0.f, 0.f};

    auto compute = [&](int cc, int buf) {
        const float4* tf = reinterpret_cast<const float4*>(&tile[buf][0]);
        const float4* xf = reinterpret_cast<const float4*>(xls) + cc * SPR;
        #pragma unroll 4
        for (int kk = 0; kk < SPR; ++kk) {
            const int p = kk ^ (t & 7);                 // de-swizzle
            const float4 s4 = tf[(t << 4) + p];
            const f32x2 sa = {s4.x, s4.y};
            const f32x2 sb = {s4.z, s4.w};
            const float4 x0 = xf[0 * (D / 4) + kk];     // broadcast ds_read_b128
            const float4 x1 = xf[1 * (D / 4) + kk];
            const float4 x2 = xf[2 * (D / 4) + kk];
            const float4 x3 = xf[3 * (D / 4) + kk];
            ssq = __builtin_elementwise_fma(sa, sa, ssq);
            ssq = __builtin_elementwise_fma(sb, sb, ssq);
            d0 = __builtin_elementwise_fma(sa, (f32x2){x0.x, x0.y}, d0);
            d0 = __builtin_elementwise_fma(sb, (f32x2){x0.z, x0.w}, d0);
            d1 = __builtin_elementwise_fma(sa, (f32x2){x1.x, x1.y}, d1);
            d1 = __builtin_elementwise_fma(sb, (f32x2){x1.z, x1.w}, d1);
            d2 = __builtin_elementwise_fma(sa, (f32x2){x2.x, x2.y}, d2);
            d2 = __builtin_elementwise_fma(sb, (f32x2){x2.z, x2.w}, d2);
            d3 = __builtin_elementwise_fma(sa, (f32x2){x3.x, x3.y}, d3);
            d3 = __builtin_elementwise_fma(sb, (f32x2){x3.z, x3.w}, d3);
        }
        // all ds_reads of this buffer consumed before next gld16 targets it
        asm volatile("s_waitcnt lgkmcnt(0)" ::: "memory");
        __builtin_amdgcn_sched_barrier(0);
    };

    // barrier-free counted-vmcnt pipeline (single wave owns the whole block)
    stage(0, 0);
    stage(1, 1);

    asm volatile("s_waitcnt vmcnt(16)" ::: "memory");  // x + c0 done
    __builtin_amdgcn_sched_barrier(0);
    compute(0, 0);
    stage(2, 0);

    asm volatile("s_waitcnt vmcnt(16)" ::: "memory");  // c1 done
    __builtin_amdgcn_sched_barrier(0);
    compute(1, 1);
    stage(3, 1);

    asm volatile("s_waitcnt vmcnt(16)" ::: "memory");  // c2 done
    __builtin_amdgcn_sched_barrier(0);
    compute(2, 0);

    asm volatile("s_waitcnt vmcnt(0)" ::: "memory");   // c3 done
    __builtin_amdgcn_sched_barrier(0);
    compute(3, 1);

    // ---- epilogue: score -> exp -> 32-lane reduce per set ----
    const int   rloc = t & (RPS - 1);
    const int   set  = t >> 5;            // 0 = sv1 rows, 1 = sv0 rows
    const float av   = set ? a0[rg * RPS + rloc] : a1[rg * RPS + rloc];
    const float lal  = __logf(av);
    const float sq   = ssq.x + ssq.y;

    float e0 = __expf(G * (sq - 2.f * (d0.x + d0.y)) - lal - CSH);
    float e1 = __expf(G * (sq - 2.f * (d1.x + d1.y)) - lal - CSH);
    float e2 = __expf(G * (sq - 2.f * (d2.x + d2.y)) - lal - CSH);
    float e3 = __expf(G * (sq - 2.f * (d3.x + d3.y)) - lal - CSH);

    #pragma unroll
    for (int off = 16; off > 0; off >>= 1) {   // reduce within 32-lane halves
        e0 += __shfl_xor(e0, off);
        e1 += __shfl_xor(e1, off);
        e2 += __shfl_xor(e2, off);
        e3 += __shfl_xor(e3, off);
    }
    if (t == 0 || t == 32) {
        float* dst = ws + (size_t)set * (RG * B) + rg * B + bbase;
        dst[0] = e0; dst[1] = e1; dst[2] = e2; dst[3] = e3;
    }

    // ---- grid-wide combine: out[b] = log(S0) - log(S1) (CSH cancels) ----
    __threadfence();
    cg::this_grid().sync();

    const int bid = blockIdx.y * RG + blockIdx.x;   // 0..1023
    if (bid < B / NT) {                             // blocks 0..3
        const int b = bid * NT + t;
        float S1 = 0.f, S0 = 0.f;
        #pragma unroll
        for (int rg2 = 0; rg2 < RG; ++rg2) {
            S1 += ws[rg2 * B + b];
            S0 += ws[RG * B + rg2 * B + b];
        }
        out[b] = __logf(S0) - __logf(S1);
    }
}

extern "C" void kernel_launch(void* const* d_in, const int* in_sizes, int n_in,
                              void* d_out, int out_size, void* d_ws, size_t ws_size,
                              hipStream_t stream) {
    const float* x   = (const float*)d_in[0];
    const float* sv1 = (const float*)d_in[1];
    const float* sv0 = (const float*)d_in[2];
    const float* a1  = (const float*)d_in[3];
    const float* a0  = (const float*)d_in[4];
    float* ws  = (float*)d_ws;
    float* out = (float*)d_out;

    dim3 grid(RG, B / NB);   // 16 x 64 = 1024 single-wave blocks (4/CU, LDS-exact)
    dim3 block(NT);
    void* args[] = {(void*)&x, (void*)&sv1, (void*)&sv0,
                    (void*)&a1, (void*)&a0, (void*)&ws, (void*)&out};
    hipLaunchCooperativeKernel(reinterpret_cast<void*>(k_coop),
                               grid, block, args, 0, stream);
}

// Round 9
// 14.352 us; speedup vs baseline: 11.3751x; 11.3751x over previous
//
#include <hip/hip_runtime.h>
#include <math.h>

static constexpr int   B    = 256;   // batch
static constexpr int   D    = 256;   // feature dim
static constexpr int   NSV  = 512;   // P == Q
static constexpr int   RG   = 16;    // SV row-group slices
static constexpr int   RPS  = NSV / RG;   // 32 rows per set per block
static constexpr int   RPB  = 2 * RPS;    // 64 tile rows (set1 then set0)
static constexpr int   NB   = 4;          // batches per block
static constexpr int   NT   = 64;         // ONE wave per block -> no barriers
static constexpr int   KC   = 64;         // chunk floats per row
static constexpr int   SPR  = KC / 4;     // 16 f4 slots per row
static constexpr float G    = 0.1f;
static constexpr float CSH  = 26.0f;      // fixed LSE shift; cancels in LSE0-LSE1

typedef float f32x2 __attribute__((ext_vector_type(2)));

__device__ __forceinline__ void gld16(const void* g, void* l) {
    __builtin_amdgcn_global_load_lds((__attribute__((address_space(1))) void*)g,
                                     (__attribute__((address_space(3))) void*)l,
                                     16, 0, 0);
}

__global__ __launch_bounds__(NT)
void k_all(const float* __restrict__ x,
           const float* __restrict__ sv1,
           const float* __restrict__ sv0,
           const float* __restrict__ a1,
           const float* __restrict__ a0,
           float* __restrict__ ws)
{
    __shared__ float tile[2][RPB * KC];   // 2 x 16 KiB SV chunk buffers

    const int t     = threadIdx.x;        // == lane; == tile row
    const int rg    = blockIdx.x;
    const int bbase = blockIdx.y * NB;
    // block-uniform x base -> compiler emits s_load (scalar cache, lgkmcnt),
    // keeping the LDS pipe for row reads and vmcnt exact for staging.
    const float* __restrict__ xw = x + (size_t)bbase * D;

    // SV chunk staging: linear LDS dest, XOR-swizzled global source (involution)
    auto stage = [&](int c, int buf) {
        #pragma unroll
        for (int i = 0; i < (RPB * SPR) / NT; ++i) {   // 16 slots/lane
            const int f  = i * NT + t;
            const int rr = f >> 4;          // tile row 0..63
            const int p  = f & 15;          // physical f4 slot
            const int q  = p ^ (rr & 7);    // logical slot
            const float* src = (rr < RPS)
                ? (sv1 + (size_t)(rg * RPS + rr) * D)
                : (sv0 + (size_t)(rg * RPS + (rr - RPS)) * D);
            gld16(src + c * KC + q * 4, &tile[buf][f * 4]);
        }
    };

    f32x2 ssq = {0.f, 0.f};
    f32x2 d0 = {0.f, 0.f}, d1 = {0.f, 0.f}, d2 = {0.f, 0.f}, d3 = {0.f, 0.f};

    auto compute = [&](int cc, int buf) {
        const float4* tf = reinterpret_cast<const float4*>(&tile[buf][0]);
        const float*  xc = xw + cc * KC;
        #pragma unroll 4
        for (int kk = 0; kk < SPR; ++kk) {
            const int p = kk ^ (t & 7);                 // de-swizzle
            const float4 s4 = tf[(t << 4) + p];
            const f32x2 sa = {s4.x, s4.y};
            const f32x2 sb = {s4.z, s4.w};
            const float4 x0 = *reinterpret_cast<const float4*>(xc + 0 * D + kk * 4);
            const float4 x1 = *reinterpret_cast<const float4*>(xc + 1 * D + kk * 4);
            const float4 x2 = *reinterpret_cast<const float4*>(xc + 2 * D + kk * 4);
            const float4 x3 = *reinterpret_cast<const float4*>(xc + 3 * D + kk * 4);
            ssq = __builtin_elementwise_fma(sa, sa, ssq);
            ssq = __builtin_elementwise_fma(sb, sb, ssq);
            d0 = __builtin_elementwise_fma(sa, (f32x2){x0.x, x0.y}, d0);
            d0 = __builtin_elementwise_fma(sb, (f32x2){x0.z, x0.w}, d0);
            d1 = __builtin_elementwise_fma(sa, (f32x2){x1.x, x1.y}, d1);
            d1 = __builtin_elementwise_fma(sb, (f32x2){x1.z, x1.w}, d1);
            d2 = __builtin_elementwise_fma(sa, (f32x2){x2.x, x2.y}, d2);
            d2 = __builtin_elementwise_fma(sb, (f32x2){x2.z, x2.w}, d2);
            d3 = __builtin_elementwise_fma(sa, (f32x2){x3.x, x3.y}, d3);
            d3 = __builtin_elementwise_fma(sb, (f32x2){x3.z, x3.w}, d3);
        }
        // tile ds_reads consumed before the next gld16 overwrites this buffer
        asm volatile("s_waitcnt lgkmcnt(0)" ::: "memory");
        __builtin_amdgcn_sched_barrier(0);
    };

    // barrier-free counted-vmcnt pipeline (single wave owns the whole block)
    stage(0, 0);
    stage(1, 1);

    asm volatile("s_waitcnt vmcnt(16)" ::: "memory");  // c0 done
    __builtin_amdgcn_sched_barrier(0);
    compute(0, 0);
    stage(2, 0);

    asm volatile("s_waitcnt vmcnt(16)" ::: "memory");  // c1 done
    __builtin_amdgcn_sched_barrier(0);
    compute(1, 1);
    stage(3, 1);

    asm volatile("s_waitcnt vmcnt(16)" ::: "memory");  // c2 done
    __builtin_amdgcn_sched_barrier(0);
    compute(2, 0);

    asm volatile("s_waitcnt vmcnt(0)" ::: "memory");   // c3 done
    __builtin_amdgcn_sched_barrier(0);
    compute(3, 1);

    // ---- epilogue: score -> exp -> 32-lane reduce per set ----
    const int   rloc = t & (RPS - 1);
    const int   set  = t >> 5;            // 0 = sv1 rows, 1 = sv0 rows
    const float av   = set ? a0[rg * RPS + rloc] : a1[rg * RPS + rloc];
    const float lal  = __logf(av);
    const float sq   = ssq.x + ssq.y;

    float e0 = __expf(G * (sq - 2.f * (d0.x + d0.y)) - lal - CSH);
    float e1 = __expf(G * (sq - 2.f * (d1.x + d1.y)) - lal - CSH);
    float e2 = __expf(G * (sq - 2.f * (d2.x + d2.y)) - lal - CSH);
    float e3 = __expf(G * (sq - 2.f * (d3.x + d3.y)) - lal - CSH);

    #pragma unroll
    for (int off = 16; off > 0; off >>= 1) {   // reduce within 32-lane halves
        e0 += __shfl_xor(e0, off);
        e1 += __shfl_xor(e1, off);
        e2 += __shfl_xor(e2, off);
        e3 += __shfl_xor(e3, off);
    }
    if (t == 0 || t == 32) {
        float* dst = ws + (size_t)set * (RG * B) + rg * B + bbase;
        dst[0] = e0; dst[1] = e1; dst[2] = e2; dst[3] = e3;
    }
}

// out[b] = log(S0) - log(S1); the CSH shift cancels exactly.
__global__ __launch_bounds__(B)
void k_final(const float* __restrict__ ws, float* __restrict__ out)
{
    const int b = threadIdx.x;
    float S1 = 0.f, S0 = 0.f;
    #pragma unroll
    for (int rg = 0; rg < RG; ++rg) {
        S1 += ws[rg * B + b];
        S0 += ws[RG * B + rg * B + b];
    }
    out[b] = __logf(S0) - __logf(S1);
}

extern "C" void kernel_launch(void* const* d_in, const int* in_sizes, int n_in,
                              void* d_out, int out_size, void* d_ws, size_t ws_size,
                              hipStream_t stream) {
    const float* x   = (const float*)d_in[0];
    const float* sv1 = (const float*)d_in[1];
    const float* sv0 = (const float*)d_in[2];
    const float* a1  = (const float*)d_in[3];
    const float* a0  = (const float*)d_in[4];
    float* ws  = (float*)d_ws;
    float* out = (float*)d_out;

    dim3 g1(RG, B / NB);   // 16 x 64 = 1024 single-wave blocks
    k_all<<<g1, NT, 0, stream>>>(x, sv1, sv0, a1, a0, ws);
    k_final<<<1, B, 0, stream>>>(ws, out);
}